// Round 1
// baseline (329.507 us; speedup 1.0000x reference)
//
#include <hip/hip_runtime.h>
#include <math.h>

// CTC batch cost (Keras ctc_batch_cost semantics) on gfx950.
// B=256, T=512, V=256 (blank = V-1 = 255), L=64, S = 2L+1 = 129.
//
// Mapping: one block = one wave (64 lanes) = one batch element.
//   lane L owns extended states s=2L (blank) and s=2L+1 (label L);
//   lane 63 additionally owns s=128 (final blank) privately — its
//   predecessors (alpha[128], alpha[127]) are both lane-63-local.
// Cross-lane need per step: alpha[2L-1] = prev lane's odd state -> one
// __shfl_up. Single-wave block => wave-synchronous, no __syncthreads.
//
// y_pred rows are streamed through LDS in double-buffered tiles of
// TT=16 timesteps (16 KiB/tile), loaded as coalesced float4 into
// registers while the current tile's DP runs, then written to LDS.

#define BB   256
#define TI   512
#define VV   256
#define LL   64
#define TT   16                 // timesteps per LDS tile
#define NTILES (TI / TT)        // 32
#define EPSF 1e-7f
#define NEGF -1e30f

__device__ __forceinline__ float lae(float a, float b) {
    // logaddexp, stable; exact pass-through of -1e30 "log zero" values
    float mx = fmaxf(a, b);
    float mn = fminf(a, b);
    return mx + __logf(1.0f + __expf(mn - mx));
}

__global__ __launch_bounds__(64) void ctc_kernel(
        const int* __restrict__ y_true,     // [B, L] int32, values in [0, V-1)
        const float* __restrict__ y_pred,   // [B, T, V] float32 (softmax probs)
        float* __restrict__ out) {          // [B] float32
    __shared__ float lds[2][TT * VV];

    const int b    = blockIdx.x;
    const int lane = threadIdx.x;   // 0..63
    const float* src = y_pred + (size_t)b * TI * VV;

    // label for this lane's odd state, and the skip flag
    const int myLab = y_true[b * LL + lane];
    int prevLab = __shfl_up(myLab, 1);
    // s=1 (lane 0): reference sets skip=true but alpha[-1]=NEG anyway; our
    // shuffled predecessor is masked to NEG at lane 0, so skip=true is safe.
    const bool skip = (lane == 0) ? true : (myLab != prevLab);

    // ---- prologue: stage tile 0 into LDS buffer 0 ----
    float4 reg[16];                          // 16 float4 = one 16 KiB tile / 64 lanes
    {
        const float4* g = (const float4*)src;
        #pragma unroll
        for (int i = 0; i < 16; ++i) reg[i] = g[i * 64 + lane];
        float4* d = (float4*)lds[0];
        #pragma unroll
        for (int i = 0; i < 16; ++i) d[i * 64 + lane] = reg[i];
    }

    float a0   = NEGF;   // alpha[2L]
    float a1   = NEGF;   // alpha[2L+1]
    float a128 = NEGF;   // alpha[128] (meaningful on lane 63 only)

    for (int k = 0; k < NTILES; ++k) {
        const float* cur = lds[k & 1];
        float*       nxt = lds[(k + 1) & 1];

        // issue next tile's global loads (overlap with this tile's DP)
        if (k + 1 < NTILES) {
            const float4* g = (const float4*)(src + (size_t)(k + 1) * TT * VV);
            #pragma unroll
            for (int i = 0; i < 16; ++i) reg[i] = g[i * 64 + lane];
        }

        #pragma unroll
        for (int tt = 0; tt < TT; ++tt) {
            const float xb = cur[tt * VV + (VV - 1)];   // blank prob (broadcast)
            const float xl = cur[tt * VV + myLab];      // this lane's label prob
            const float lpb = __logf(xb + EPSF);
            const float lpl = __logf(xl + EPSF);

            const int t = k * TT + tt;
            if (t == 0) {
                // alpha0: only s=0 and s=1 reachable
                a0   = (lane == 0) ? lpb : NEGF;
                a1   = (lane == 0) ? lpl : NEGF;
                a128 = NEGF;
            } else {
                float pa1 = __shfl_up(a1, 1);           // alpha[2L-1]
                if (lane == 0) pa1 = NEGF;              // alpha[-1]

                // s = 2L (blank): from alpha[2L], alpha[2L-1]
                const float na0 = lae(a0, pa1) + lpb;
                // s = 2L+1 (label): from alpha[2L+1], alpha[2L], (skip) alpha[2L-1]
                float m = lae(a1, a0);
                if (skip) m = lae(m, pa1);
                const float na1 = m + lpl;
                // s = 128 (lane 63): from alpha[128], alpha[127]
                const float na128 = lae(a128, a1) + lpb;

                a0 = na0; a1 = na1; a128 = na128;
            }
        }

        // commit next tile to the other LDS buffer
        if (k + 1 < NTILES) {
            float4* d = (float4*)nxt;
            #pragma unroll
            for (int i = 0; i < 16; ++i) d[i * 64 + lane] = reg[i];
        }
    }

    // loss = -logaddexp(alpha[128], alpha[127]); both live on lane 63
    if (lane == 63) out[b] = -lae(a128, a1);
}

extern "C" void kernel_launch(void* const* d_in, const int* in_sizes, int n_in,
                              void* d_out, int out_size, void* d_ws, size_t ws_size,
                              hipStream_t stream) {
    const int*   y_true = (const int*)d_in[0];
    const float* y_pred = (const float*)d_in[1];
    float*       out    = (float*)d_out;
    ctc_kernel<<<dim3(BB), dim3(64), 0, stream>>>(y_true, y_pred, out);
}

// Round 2
// 202.894 us; speedup vs baseline: 1.6240x; 1.6240x over previous
//
#include <hip/hip_runtime.h>
#include <math.h>

// CTC batch cost (Keras ctc_batch_cost), gfx950. B=256,T=512,V=256,L=64,S=129.
//
// One wave = one batch element. Lane L owns states 2L (blank) and 2L+1
// (label L); lane 63 also owns s=128 privately. Per-step cross-lane dep
// (alpha[2L-1]) via DPP wave_shr:1 (VALU, ~2cy) instead of ds_permute.
// DP runs entirely on registers in log2 domain; log-probs for each
// 16-step tile are extracted from LDS and v_log'd one tile AHEAD so the
// LDS latency hides in the DP chain's issue gaps. y_pred streams via
// global_load_lds (16B/lane), triple-buffered, issued 2 tiles ahead,
// synchronized with explicit s_waitcnt vmcnt(16).

#define BB   256
#define TI   512
#define VV   256
#define LL   64
#define TT   16
#define NT   (TI / TT)          // 32 tiles
#define EPSF 1e-7f
#define NEGF -1e30f
#define LN2F 0.6931471805599453f

#if __has_builtin(__builtin_amdgcn_exp2f)
__device__ __forceinline__ float fexp2(float x) { return __builtin_amdgcn_exp2f(x); }
#else
__device__ __forceinline__ float fexp2(float x) { return __exp2f(x); }
#endif
#if __has_builtin(__builtin_amdgcn_logf)
__device__ __forceinline__ float flog2(float x) { return __builtin_amdgcn_logf(x); }
#else
__device__ __forceinline__ float flog2(float x) { return __log2f(x); }
#endif

// lane i <- lane i-1; lane 0 <- NEGF.  v_mov_b32_dpp wave_shr:1
__device__ __forceinline__ float shup_neg(float x) {
    int r = __builtin_amdgcn_update_dpp(__float_as_int(NEGF), __float_as_int(x),
                                        0x138 /*DPP_WF_SR1*/, 0xF, 0xF, false);
    return __int_as_float(r);
}

// logaddexp in log2 domain
__device__ __forceinline__ float lae2(float a, float b) {
    float m = fmaxf(a, b);
    float d = fminf(a, b) - m;
    return m + flog2(1.0f + fexp2(d));
}
__device__ __forceinline__ float lae3(float a, float b, float c) {
    float m = fmaxf(fmaxf(a, b), c);   // v_max3_f32
    float s = fexp2(a - m) + fexp2(b - m) + fexp2(c - m);
    return m + flog2(s);
}

__device__ __forceinline__ void dp_step(float& a0, float& a1, float& a128,
                                        float lpb, float lpl, bool skip) {
    float pa1  = shup_neg(a1);                 // alpha[2L-1]
    float pa1s = skip ? pa1 : NEGF;
    float na0   = lae2(a0, pa1) + lpb;         // s = 2L
    float na1   = lae3(a1, a0, pa1s) + lpl;    // s = 2L+1
    float na128 = lae2(a128, a1) + lpb;        // s = 128 (lane 63)
    a0 = na0; a1 = na1; a128 = na128;
}

// stage one 16-timestep tile (16 KB) global -> LDS, no registers
__device__ __forceinline__ void stage_tile(const float* gsrc, float* lbase, int lane) {
    #pragma unroll
    for (int i = 0; i < TT; ++i) {
        __builtin_amdgcn_global_load_lds(
            (const __attribute__((address_space(1))) void*)(gsrc + i * VV + lane * 4),
            (__attribute__((address_space(3))) void*)(lbase + i * VV),
            16, 0, 0);
    }
}

__device__ __forceinline__ void prep_lp(const float* sb, int myLab,
                                        float (&lpb)[TT], float (&lpl)[TT]) {
    #pragma unroll
    for (int tt = 0; tt < TT; ++tt) {
        float xb = sb[tt * VV + (VV - 1)];
        float xl = sb[tt * VV + myLab];
        lpb[tt] = flog2(xb + EPSF);
        lpl[tt] = flog2(xl + EPSF);
    }
}

__global__ __launch_bounds__(64) void ctc_kernel(
        const int* __restrict__ y_true,
        const float* __restrict__ y_pred,
        float* __restrict__ out) {
    __shared__ float sbuf[3 * TT * VV];        // 48 KB triple buffer

    const int b    = blockIdx.x;
    const int lane = threadIdx.x;
    const float* src = y_pred + (size_t)b * TI * VV;

    const int myLab = y_true[b * LL + lane];
    const int prevLab = __shfl_up(myLab, 1);   // once, off hot path
    const bool skip = (lane == 0) ? true : (myLab != prevLab);

    // prologue: stage tiles 0 and 1
    stage_tile(src,               sbuf,               lane);
    stage_tile(src + TT * VV,     sbuf + TT * VV,     lane);
    asm volatile("s_waitcnt vmcnt(16)" ::: "memory");   // tile 0 resident

    float clpb[TT], clpl[TT], nlpb[TT], nlpl[TT];
    prep_lp(sbuf, myLab, clpb, clpl);

    // t = 0 init: only s=0, s=1 reachable
    float a0   = (lane == 0) ? clpb[0] : NEGF;
    float a1   = (lane == 0) ? clpl[0] : NEGF;
    float a128 = NEGF;

    for (int k = 0; k < NT; ++k) {
        if (k + 2 < NT)
            stage_tile(src + (size_t)(k + 2) * TT * VV,
                       sbuf + ((k + 2) % 3) * TT * VV, lane);

        if (k + 1 < NT) {
            if (k + 2 < NT) asm volatile("s_waitcnt vmcnt(16)" ::: "memory");
            else            asm volatile("s_waitcnt vmcnt(0)"  ::: "memory");
            prep_lp(sbuf + ((k + 1) % 3) * TT * VV, myLab, nlpb, nlpl);
        }

        if (k == 0) {
            #pragma unroll
            for (int tt = 1; tt < TT; ++tt)
                dp_step(a0, a1, a128, clpb[tt], clpl[tt], skip);
        } else {
            #pragma unroll
            for (int tt = 0; tt < TT; ++tt)
                dp_step(a0, a1, a128, clpb[tt], clpl[tt], skip);
        }

        if (k + 1 < NT) {
            #pragma unroll
            for (int tt = 0; tt < TT; ++tt) { clpb[tt] = nlpb[tt]; clpl[tt] = nlpl[tt]; }
        }
    }

    if (lane == 63) out[b] = -(lae2(a128, a1) * LN2F);
}

extern "C" void kernel_launch(void* const* d_in, const int* in_sizes, int n_in,
                              void* d_out, int out_size, void* d_ws, size_t ws_size,
                              hipStream_t stream) {
    const int*   y_true = (const int*)d_in[0];
    const float* y_pred = (const float*)d_in[1];
    float*       out    = (float*)d_out;
    ctc_kernel<<<dim3(BB), dim3(64), 0, stream>>>(y_true, y_pred, out);
}

// Round 3
// 193.935 us; speedup vs baseline: 1.6991x; 1.0462x over previous
//
#include <hip/hip_runtime.h>
#include <math.h>

// CTC batch cost (Keras ctc_batch_cost), gfx950. B=256,T=512,V=256,L=64,S=129.
//
// One wave = one batch element (256 blocks x 64 lanes). Lane L owns extended
// states 2L (blank) and 2L+1 (label L); lane 63 also owns s=128 privately.
//
// DP runs in LINEAR probability space (scaled forward algorithm):
//   na0   = (a0 + pa1) * pb
//   na1   = (a1 + a0 + skip*pa1) * pl
//   na128 = (a128 + a1) * pb          (lane 63 only meaningful)
// with pa1 = alpha[2L-1] fetched from the previous lane via DPP wave_shr:1
// (VALU, no LDS). Every 8 steps a wave-uniform max-rescale (DPP reduce +
// readlane + v_rcp) renormalizes and accumulates log2(norm) into logC.
// No transcendentals on the per-step critical path.
//
// y_pred streams via global_load_lds (16B/lane), triple-buffered 16-step
// tiles, issued 2 tiles ahead, s_waitcnt vmcnt(16); per tile only the blank
// column and each lane's label column are pulled from LDS into registers
// one tile ahead of use.

#define BB   256
#define TI   512
#define VV   256
#define LL   64
#define TT   16
#define NT   (TI / TT)          // 32 tiles
#define EPSF 1e-7f
#define LN2F 0.6931471805599453f

#if __has_builtin(__builtin_amdgcn_logf)
__device__ __forceinline__ float flog2(float x) { return __builtin_amdgcn_logf(x); }
#else
__device__ __forceinline__ float flog2(float x) { return __log2f(x); }
#endif

template <int CTRL>
__device__ __forceinline__ float dppf(float oldv, float v) {
    return __int_as_float(__builtin_amdgcn_update_dpp(
        __float_as_int(oldv), __float_as_int(v), CTRL, 0xF, 0xF, false));
}

// lane i <- lane i-1; lane 0 <- 0.0f  (v_mov_b32_dpp wave_shr:1)
__device__ __forceinline__ float shup0(float x) { return dppf<0x138>(0.0f, x); }

// wave-wide max, result broadcast via readlane(63). All inputs >= 0.
__device__ __forceinline__ float wave_max_bcast(float v) {
    v = fmaxf(v, dppf<0x111>(v, v));   // row_shr:1
    v = fmaxf(v, dppf<0x112>(v, v));   // row_shr:2
    v = fmaxf(v, dppf<0x114>(v, v));   // row_shr:4
    v = fmaxf(v, dppf<0x118>(v, v));   // row_shr:8
    v = fmaxf(v, dppf<0x142>(v, v));   // row_bcast:15
    v = fmaxf(v, dppf<0x143>(v, v));   // row_bcast:31  -> lane 63 has max
    return __int_as_float(__builtin_amdgcn_readlane(__float_as_int(v), 63));
}

__device__ __forceinline__ void rescale(float& a0, float& a1, float& a128,
                                        float& logC) {
    float m = wave_max_bcast(fmaxf(fmaxf(a0, a1), a128));
    m = fmaxf(m, 1e-37f);                       // paranoia: avoid 1/0
    float s = __builtin_amdgcn_rcpf(m);
    a0 *= s; a1 *= s; a128 *= s;
    logC += flog2(m);
}

__device__ __forceinline__ void dp_step(float& a0, float& a1, float& a128,
                                        float pb, float pl, float skipf) {
    float pa1 = shup0(a1);                      // alpha[2L-1]
    float s01 = a0 + a1;
    float t0  = a0 + pa1;
    float na1   = fmaf(pa1, skipf, s01) * pl;   // (a1+a0+skip*pa1)*pl
    float na0   = t0 * pb;                      // (a0+pa1)*pb
    float na128 = (a128 + a1) * pb;             // lane 63
    a0 = na0; a1 = na1; a128 = na128;
}

// stage one 16-timestep tile (16 KB) global -> LDS
__device__ __forceinline__ void stage_tile(const float* gsrc, float* lbase, int lane) {
    #pragma unroll
    for (int i = 0; i < TT; ++i) {
        __builtin_amdgcn_global_load_lds(
            (const __attribute__((address_space(1))) void*)(gsrc + i * VV + lane * 4),
            (__attribute__((address_space(3))) void*)(lbase + i * VV),
            16, 0, 0);
    }
}

// pull blank + own-label probabilities (with +eps folded in) into registers
__device__ __forceinline__ void prep_p(const float* sb, int myLab,
                                       float (&pb)[TT], float (&pl)[TT]) {
    #pragma unroll
    for (int tt = 0; tt < TT; ++tt) {
        pb[tt] = sb[tt * VV + (VV - 1)] + EPSF;
        pl[tt] = sb[tt * VV + myLab]    + EPSF;
    }
}

__global__ __launch_bounds__(64) void ctc_kernel(
        const int* __restrict__ y_true,
        const float* __restrict__ y_pred,
        float* __restrict__ out) {
    __shared__ float sbuf[3 * TT * VV];        // 48 KB triple buffer

    const int b    = blockIdx.x;
    const int lane = threadIdx.x;
    const float* src = y_pred + (size_t)b * TI * VV;

    const int myLab   = y_true[b * LL + lane];
    const int prevLab = __shfl_up(myLab, 1);   // once, off hot path
    const float skipf = (lane == 0 || myLab != prevLab) ? 1.0f : 0.0f;

    // prologue: stage tiles 0 and 1
    stage_tile(src,           sbuf,           lane);
    stage_tile(src + TT * VV, sbuf + TT * VV, lane);
    asm volatile("s_waitcnt vmcnt(16)" ::: "memory");   // tile 0 resident

    float cpb[TT], cpl[TT], npb[TT], npl[TT];
    prep_p(sbuf, myLab, cpb, cpl);

    // t = 0 init: only s=0, s=1 reachable (lane 0)
    float a0   = (lane == 0) ? cpb[0] : 0.0f;
    float a1   = (lane == 0) ? cpl[0] : 0.0f;
    float a128 = 0.0f;
    float logC = 0.0f;

    for (int k = 0; k < NT; ++k) {
        if (k + 2 < NT)
            stage_tile(src + (size_t)(k + 2) * TT * VV,
                       sbuf + ((k + 2) % 3) * TT * VV, lane);

        if (k + 1 < NT) {
            if (k + 2 < NT) asm volatile("s_waitcnt vmcnt(16)" ::: "memory");
            else            asm volatile("s_waitcnt vmcnt(0)"  ::: "memory");
            prep_p(sbuf + ((k + 1) % 3) * TT * VV, myLab, npb, npl);
        }

        #pragma unroll
        for (int tt = 0; tt < TT; ++tt) {
            if (!(k == 0 && tt == 0))
                dp_step(a0, a1, a128, cpb[tt], cpl[tt], skipf);
            if ((tt & 7) == 7)
                rescale(a0, a1, a128, logC);   // every 8 steps
        }

        if (k + 1 < NT) {
            #pragma unroll
            for (int tt = 0; tt < TT; ++tt) { cpb[tt] = npb[tt]; cpl[tt] = npl[tt]; }
        }
    }

    // loss = -ln(P) = -ln2 * (logC + log2(alpha[128] + alpha[127])), on lane 63
    if (lane == 63) {
        float tail = fmaxf(a128 + a1, 1e-37f);
        out[b] = -LN2F * (logC + flog2(tail));
    }
}

extern "C" void kernel_launch(void* const* d_in, const int* in_sizes, int n_in,
                              void* d_out, int out_size, void* d_ws, size_t ws_size,
                              hipStream_t stream) {
    const int*   y_true = (const int*)d_in[0];
    const float* y_pred = (const float*)d_in[1];
    float*       out    = (float*)d_out;
    ctc_kernel<<<dim3(BB), dim3(64), 0, stream>>>(y_true, y_pred, out);
}